// Round 3
// baseline (620.687 us; speedup 1.0000x reference)
//
#include <hip/hip_runtime.h>

// Problem constants (fixed shapes from setup_inputs)
#define B 8
#define I 32
#define O 32
#define D 8
#define H 14
#define W 14
#define K 9
#define WK (W*K)              // 126
#define DSTRIDE (H*W*K)       // 1764
#define OSTRIDE (D*H*W*K)     // 14112
#define ISTRIDE (O*D*H*W*K)   // 451584
#define BSTRIDE ((size_t)I*ISTRIDE)
#define SUBSET 26             // ceil(0.8 * 32)
#define SLAB (D*H*WK)         // 14112 floats per (b,i,o) slab (contiguous!)
#define SLAB4 (SLAB/4)        // 3528 float4
#define YS_BLOCK (I*W*D)      // 3584 floats of ys per (b,o,h)

// ---------------- Kernel 1: K-reduction ----------------
// One block per (b,i,o). The slab x[b,i,o,:,:,:,:] is 14112 contiguous
// 16B-aligned floats -> perfectly coalesced float4 staging into LDS.
// Then: nk[h,w,k] = ||x[.,d,.]||_D ; y[d,h,w] = sum_k nk*x / sum_k nk.
// Write ys to ws in layout [b][o][h][i][w][d] (contiguous 32B per thread).
__global__ __launch_bounds__(256) void k_reduce(const float* __restrict__ x,
                                                float* __restrict__ ys) {
    const int bid = blockIdx.x;           // (b*I + i)*O + o
    const int o = bid % O;
    const int i = (bid / O) % I;
    const int b = bid / (O * I);
    const int t = threadIdx.x;

    __shared__ float xs[SLAB];      // 56448 B
    __shared__ float nk[DSTRIDE];   // 7056 B

    const float4* src = (const float4*)(x + (size_t)b * BSTRIDE
                                          + (size_t)i * ISTRIDE
                                          + (size_t)o * OSTRIDE);
    float4* xs4 = (float4*)xs;
    #pragma unroll
    for (int it = 0; it < 14; ++it) {
        int idx = it * 256 + t;
        if (idx < SLAB4) xs4[idx] = src[idx];
    }
    __syncthreads();

    // nk[j], j = h*126 + w*9 + k  (lanes j consecutive -> conflict-free)
    #pragma unroll
    for (int it = 0; it < 7; ++it) {
        int j = it * 256 + t;
        if (j < DSTRIDE) {
            float s = 0.f;
            #pragma unroll
            for (int d = 0; d < D; ++d) { float v = xs[d * DSTRIDE + j]; s += v * v; }
            nk[j] = sqrtf(s);
        }
    }
    __syncthreads();

    // one thread per (h,w): K-weighted average over k for all d
    if (t < H * W) {
        const int h = t / W, w = t - (t / W) * W;
        const int jb = h * WK + w * K;
        float nkv[K];
        float den = 0.f;
        #pragma unroll
        for (int k = 0; k < K; ++k) { nkv[k] = nk[jb + k]; den += nkv[k]; }
        const float inv = 1.f / den;
        float y[D];
        #pragma unroll
        for (int d = 0; d < D; ++d) {
            float num = 0.f;
            #pragma unroll
            for (int k = 0; k < K; ++k) num += nkv[k] * xs[d * DSTRIDE + jb + k];
            y[d] = num * inv;
        }
        // ws layout [b][o][h][i][w][d]: 32B-aligned contiguous per thread
        float4* dst = (float4*)(ys + ((((size_t)(b * O + o) * H + h) * I + i) * W + w) * D);
        dst[0] = make_float4(y[0], y[1], y[2], y[3]);
        dst[1] = make_float4(y[4], y[5], y[6], y[7]);
    }
}

// ---------------- Kernel 2: routing ----------------
// One block per (b,o,h), 448 threads = (i,w). Reads the contiguous
// [i][w][d] ys slab (14336 B), recomputes ns from registers, then
// consensus / losses / kth-smallest (stable rank) / masked average.
__global__ __launch_bounds__(448) void k_route(const float* __restrict__ ys,
                                               float* __restrict__ out) {
    const int bid = blockIdx.x;  // (b*O + o)*H + h
    const int h = bid % H;
    const int o = (bid / H) % O;
    const int b = bid / (H * O);
    const int t = threadIdx.x;
    const int i = t / W, w = t - (t / W) * W;   // t == i*W + w

    __shared__ float ysl[YS_BLOCK];  // [i][w][d]  (14336 B)
    __shared__ float ns_s[I * W];    // [i][w]
    __shared__ float ls_s[I * W];    // [i][w]
    __shared__ float vsh[D * W];     // [d][w]
    __shared__ float thr_s[W];

    const float4* src = (const float4*)(ys + (size_t)bid * YS_BLOCK);
    float4* ysl4 = (float4*)ysl;
    ysl4[t] = src[t];
    ysl4[t + 448] = src[t + 448];
    __syncthreads();

    // per-thread y + ns (contiguous 8 floats at t*8 -> ds_read_b128 x2)
    float y[D];
    float s2 = 0.f;
    #pragma unroll
    for (int d = 0; d < D; ++d) { y[d] = ysl[t * D + d]; s2 += y[d] * y[d]; }
    const float nsv = sqrtf(s2);
    ns_s[t] = nsv;
    __syncthreads();

    // consensus v[d][w] (112 threads)
    if (t < D * W) {
        const int d = t / W, w2 = t - (t / W) * W;
        float num = 0.f, dn = 0.f;
        #pragma unroll
        for (int j = 0; j < I; ++j) {
            float nv = ns_s[j * W + w2];
            num += nv * ysl[(j * W + w2) * D + d];
            dn += nv;
        }
        vsh[d * W + w2] = num / dn;
    }
    __syncthreads();

    // losses (all 448 threads; y in regs)
    float lv = 0.f;
    #pragma unroll
    for (int d = 0; d < D; ++d) lv += vsh[d * W + w] * y[d];
    lv = -lv;
    ls_s[t] = lv;
    __syncthreads();

    // kth smallest (k=SUBSET) via stable rank -> matches jnp.sort[...,25]
    int rank = 0;
    #pragma unroll
    for (int j = 0; j < I; ++j) {
        float lj = ls_s[j * W + w];
        rank += (lj < lv || (lj == lv && j < i)) ? 1 : 0;
    }
    if (rank == SUBSET - 1) thr_s[w] = lv;
    __syncthreads();

    // masked weighted average -> out[b][o][d][h][w] (112 threads)
    if (t < D * W) {
        const int d = t / W, w2 = t - (t / W) * W;
        const float tw = thr_s[w2];
        float num = 0.f, dn = 0.f;
        #pragma unroll
        for (int j = 0; j < I; ++j) {
            float ls = ls_s[j * W + w2];
            float m  = (ls <= tw) ? 1.f : 0.f;
            float nv = m * ns_s[j * W + w2];
            num += nv * ysl[(j * W + w2) * D + d];
            dn  += nv;
        }
        out[(((size_t)b * O + o) * D + d) * (H * W) + h * W + w2] = num / dn;
    }
}

extern "C" void kernel_launch(void* const* d_in, const int* in_sizes, int n_in,
                              void* d_out, int out_size, void* d_ws, size_t ws_size,
                              hipStream_t stream) {
    const float* x = (const float*)d_in[0];
    float* out = (float*)d_out;
    float* ys = (float*)d_ws;   // 12,845,056 floats = 51.4 MB < ws_size

    k_reduce<<<dim3(B * I * O), dim3(256), 0, stream>>>(x, ys);
    k_route<<<dim3(B * O * H), dim3(448), 0, stream>>>(ys, out);
}

// Round 4
// 616.872 us; speedup vs baseline: 1.0062x; 1.0062x over previous
//
#include <hip/hip_runtime.h>

// Problem constants (fixed shapes from setup_inputs)
#define B 8
#define I 32
#define O 32
#define D 8
#define H 14
#define W 14
#define K 9
#define WK (W*K)              // 126
#define DSTRIDE (H*W*K)       // 1764
#define OSTRIDE (D*H*W*K)     // 14112
#define ISTRIDE (O*D*H*W*K)   // 451584
#define BSTRIDE ((size_t)I*ISTRIDE)
#define SUBSET 26             // ceil(0.8 * 32)
#define YS_BLOCK (I*W*D)      // 3584 floats of ys per (b,o,h)

// ---------------- Kernel 1: K-reduction (occupancy-tuned) ----------------
// One block per (b,i,o) slab, 256 threads, 7 iterations of 2 rows (h) each.
// Per iteration: stage [D][2 rows][126] = 2016 floats (1008 float2, fully
// coalesced: per d a contiguous 126-float2 run) into double-buffered LDS
// (~18 KB total -> 8 blocks/CU, all 2048 blocks co-resident), compute
// per-(h,w,k) D-norms, K-weighted average, write ys[b][o][h][i][w][d].
__global__ __launch_bounds__(256) void k_reduce(const float* __restrict__ x,
                                                float* __restrict__ ys) {
    const int bid = blockIdx.x;           // (b*I + i)*O + o
    const int o = bid % O;
    const int i = (bid / O) % I;
    const int b = bid / (O * I);
    const int t = threadIdx.x;

    __shared__ float xs[2][D * 252];   // [buf][d][2 rows * 126]  (16128 B)
    __shared__ float nkl[2][256];      // [buf][row*126 + w*9+k]  (2048 B)

    const float2* src = (const float2*)(x + (size_t)b * BSTRIDE
                                          + (size_t)i * ISTRIDE
                                          + (size_t)o * OSTRIDE);
    // float2 view of slab: [d][882]; double-row rr of d starts at d*882+rr*126
    const int f0 = t, f1 = t + 256, f2 = t + 512, f3 = t + 768;
    const int d0 = f0 / 126, j0 = f0 - d0 * 126;
    const int d1 = f1 / 126, j1 = f1 - d1 * 126;
    const int d2 = f2 / 126, j2 = f2 - d2 * 126;
    const int d3 = f3 / 126, j3 = f3 - d3 * 126;
    const bool v3 = (f3 < 1008);

    const float2* p0 = src + d0 * 882 + j0;
    const float2* p1 = src + d1 * 882 + j1;
    const float2* p2 = src + d2 * 882 + j2;
    const float2* p3 = src + d3 * 882 + j3;

    float2 r0 = p0[0];
    float2 r1 = p1[0];
    float2 r2 = p2[0];
    float2 r3 = v3 ? p3[0] : make_float2(0.f, 0.f);

    // ys index = ((bo*H + h)*I + i)*112 + rem
    float* ybase = ys + ((size_t)(b * O + o) * H * I + i) * (W * D);

    // y-phase mapping (t < 224): row = t/112, w = (t%112)/8, d = (t%112)%8
    const int row_y = t / 112;
    const int rem_y = t - row_y * 112;
    const int w_y = rem_y >> 3, d_y = rem_y & 7;

    for (int rr = 0; rr < 7; ++rr) {
        const int buf = rr & 1;
        // ---- store staged double-row into LDS ----
        xs[buf][d0 * 252 + 2 * j0]     = r0.x;
        xs[buf][d0 * 252 + 2 * j0 + 1] = r0.y;
        xs[buf][d1 * 252 + 2 * j1]     = r1.x;
        xs[buf][d1 * 252 + 2 * j1 + 1] = r1.y;
        xs[buf][d2 * 252 + 2 * j2]     = r2.x;
        xs[buf][d2 * 252 + 2 * j2 + 1] = r2.y;
        if (v3) {
            xs[buf][d3 * 252 + 2 * j3]     = r3.x;
            xs[buf][d3 * 252 + 2 * j3 + 1] = r3.y;
        }
        __syncthreads();
        // ---- prefetch next double-row (hidden by nk phase; other resident
        //      blocks hide the rest) ----
        if (rr + 1 < 7) {
            r0 = p0[(rr + 1) * 126];
            r1 = p1[(rr + 1) * 126];
            r2 = p2[(rr + 1) * 126];
            if (v3) r3 = p3[(rr + 1) * 126];
        }
        // ---- per-(row,w,k) norm over d (252 threads, conflict-free) ----
        if (t < 252) {
            float s = 0.f;
            #pragma unroll
            for (int d = 0; d < D; ++d) { float v = xs[buf][d * 252 + t]; s += v * v; }
            nkl[buf][t] = sqrtf(s);
        }
        __syncthreads();
        // ---- K-weighted average (224 threads: 2 rows x 112) ----
        if (t < 224) {
            const int jb = row_y * 126 + w_y * K;
            float den = 0.f, num = 0.f;
            #pragma unroll
            for (int k = 0; k < K; ++k) {
                float nv = nkl[buf][jb + k];
                den += nv;
                num += nv * xs[buf][d_y * 252 + jb + k];
            }
            ybase[(size_t)(2 * rr + row_y) * (I * W * D) + rem_y] = num / den;
        }
    }
}

// ---------------- Kernel 2: routing ----------------
// One block per (b,o,h), 448 threads = (i,w). Reads the contiguous
// [i][w][d] ys slab (14336 B), recomputes ns from registers, then
// consensus / losses / kth-smallest (stable rank) / masked average.
__global__ __launch_bounds__(448) void k_route(const float* __restrict__ ys,
                                               float* __restrict__ out) {
    const int bid = blockIdx.x;  // (b*O + o)*H + h
    const int h = bid % H;
    const int o = (bid / H) % O;
    const int b = bid / (H * O);
    const int t = threadIdx.x;
    const int i = t / W, w = t - (t / W) * W;   // t == i*W + w

    __shared__ float ysl[YS_BLOCK];  // [i][w][d]  (14336 B)
    __shared__ float ns_s[I * W];    // [i][w]
    __shared__ float ls_s[I * W];    // [i][w]
    __shared__ float vsh[D * W];     // [d][w]
    __shared__ float thr_s[W];

    const float4* src = (const float4*)(ys + (size_t)bid * YS_BLOCK);
    float4* ysl4 = (float4*)ysl;
    ysl4[t] = src[t];
    ysl4[t + 448] = src[t + 448];
    __syncthreads();

    // per-thread y + ns (contiguous 8 floats at t*8 -> ds_read_b128 x2)
    float y[D];
    float s2 = 0.f;
    #pragma unroll
    for (int d = 0; d < D; ++d) { y[d] = ysl[t * D + d]; s2 += y[d] * y[d]; }
    const float nsv = sqrtf(s2);
    ns_s[t] = nsv;
    __syncthreads();

    // consensus v[d][w] (112 threads)
    if (t < D * W) {
        const int d = t / W, w2 = t - (t / W) * W;
        float num = 0.f, dn = 0.f;
        #pragma unroll
        for (int j = 0; j < I; ++j) {
            float nv = ns_s[j * W + w2];
            num += nv * ysl[(j * W + w2) * D + d];
            dn += nv;
        }
        vsh[d * W + w2] = num / dn;
    }
    __syncthreads();

    // losses (all 448 threads; y in regs)
    float lv = 0.f;
    #pragma unroll
    for (int d = 0; d < D; ++d) lv += vsh[d * W + w] * y[d];
    lv = -lv;
    ls_s[t] = lv;
    __syncthreads();

    // kth smallest (k=SUBSET) via stable rank -> matches jnp.sort[...,25]
    int rank = 0;
    #pragma unroll
    for (int j = 0; j < I; ++j) {
        float lj = ls_s[j * W + w];
        rank += (lj < lv || (lj == lv && j < i)) ? 1 : 0;
    }
    if (rank == SUBSET - 1) thr_s[w] = lv;
    __syncthreads();

    // masked weighted average -> out[b][o][d][h][w] (112 threads)
    if (t < D * W) {
        const int d = t / W, w2 = t - (t / W) * W;
        const float tw = thr_s[w2];
        float num = 0.f, dn = 0.f;
        #pragma unroll
        for (int j = 0; j < I; ++j) {
            float ls = ls_s[j * W + w2];
            float m  = (ls <= tw) ? 1.f : 0.f;
            float nv = m * ns_s[j * W + w2];
            num += nv * ysl[(j * W + w2) * D + d];
            dn  += nv;
        }
        out[(((size_t)b * O + o) * D + d) * (H * W) + h * W + w2] = num / dn;
    }
}

extern "C" void kernel_launch(void* const* d_in, const int* in_sizes, int n_in,
                              void* d_out, int out_size, void* d_ws, size_t ws_size,
                              hipStream_t stream) {
    const float* x = (const float*)d_in[0];
    float* out = (float*)d_out;
    float* ys = (float*)d_ws;   // 12,845,056 floats = 51.4 MB < ws_size

    k_reduce<<<dim3(B * I * O), dim3(256), 0, stream>>>(x, ys);
    k_route<<<dim3(B * O * H), dim3(448), 0, stream>>>(ys, out);
}

// Round 5
// 606.546 us; speedup vs baseline: 1.0233x; 1.0170x over previous
//
#include <hip/hip_runtime.h>

// Problem constants (fixed shapes from setup_inputs)
#define B 8
#define I 32
#define O 32
#define D 8
#define H 14
#define W 14
#define K 9
#define WK (W*K)              // 126
#define DSTRIDE (H*W*K)       // 1764
#define OSTRIDE (D*H*W*K)     // 14112
#define ISTRIDE (O*D*H*W*K)   // 451584
#define BSTRIDE ((size_t)I*ISTRIDE)
#define SUBSET 26             // ceil(0.8 * 32)
#define YS_BLOCK (I*W*D)      // 3584 floats of ys per (b,o,h)

typedef float f4 __attribute__((ext_vector_type(4)));

// ---------------- Kernel 1: K-reduction ----------------
// One block per (b,i,o) slab (8192 blocks), 256 threads, 7 chunks of 2 rows.
// Loads are float4 NONTEMPORAL (x is streamed exactly once per call; bypass
// L2/L3 allocate churn), fully coalesced (63 consecutive float4 per d-row).
// Double-buffered LDS (18 KB -> 8 blocks/CU = 32 waves). Compute per-(h,w,k)
// D-norms then K-weighted average; write ys[b][o][h][i][w][d].
__global__ __launch_bounds__(256) void k_reduce(const float* __restrict__ x,
                                                float* __restrict__ ys) {
    const int bid = blockIdx.x;           // (b*I + i)*O + o
    const int o = bid % O;
    const int i = (bid / O) % I;
    const int b = bid / (O * I);
    const int t = threadIdx.x;

    __shared__ __align__(16) float xs[2][D * 252];   // [buf][d][2 rows * 126]
    __shared__ float nkl[2][256];                    // [buf][row*126 + w*9+k]

    const f4* src = (const f4*)(x + (size_t)b * BSTRIDE
                                  + (size_t)i * ISTRIDE
                                  + (size_t)o * OSTRIDE);
    // chunk rr: float4 index d*441 + rr*63 + j, j in [0,63); 504 f4 per chunk
    const int g0 = t, g1 = t + 256;
    const int d0 = g0 / 63, j0 = g0 - d0 * 63;
    const int d1 = g1 / 63, j1 = g1 - d1 * 63;
    const bool v1 = (g1 < 504);

    const f4* p0 = src + d0 * 441 + j0;
    const f4* p1 = src + d1 * 441 + j1;

    f4 r0 = __builtin_nontemporal_load(p0);
    f4 r1 = v1 ? __builtin_nontemporal_load(p1) : (f4)(0.f);

    // ys base: index ((bo*H + h)*I + i)*112 + rem
    float* ybase = ys + ((size_t)(b * O + o) * H * I + i) * (W * D);

    // y-phase mapping (t < 224): row = t/112, w = (t%112)/8, d = (t%112)%8
    const int row_y = t / 112;
    const int rem_y = t - row_y * 112;
    const int w_y = rem_y >> 3, d_y = rem_y & 7;

    for (int rr = 0; rr < 7; ++rr) {
        const int buf = rr & 1;
        // ---- store staged chunk into LDS (vector, conflict-free) ----
        *(f4*)&xs[buf][d0 * 252 + 4 * j0] = r0;
        if (v1) *(f4*)&xs[buf][d1 * 252 + 4 * j1] = r1;
        __syncthreads();
        // ---- prefetch next chunk (consumed after next barrier) ----
        if (rr + 1 < 7) {
            r0 = __builtin_nontemporal_load(p0 + (rr + 1) * 63);
            if (v1) r1 = __builtin_nontemporal_load(p1 + (rr + 1) * 63);
        }
        // ---- per-(row,w,k) norm over d (252 threads, conflict-free) ----
        if (t < 252) {
            float s = 0.f;
            #pragma unroll
            for (int d = 0; d < D; ++d) { float v = xs[buf][d * 252 + t]; s += v * v; }
            nkl[buf][t] = sqrtf(s);
        }
        __syncthreads();
        // ---- K-weighted average (224 threads: 2 rows x 112) ----
        if (t < 224) {
            const int jb = row_y * 126 + w_y * K;
            float den = 0.f, num = 0.f;
            #pragma unroll
            for (int k = 0; k < K; ++k) {
                float nv = nkl[buf][jb + k];
                den += nv;
                num += nv * xs[buf][d_y * 252 + jb + k];
            }
            ybase[(size_t)(2 * rr + row_y) * (I * W * D) + rem_y] = num / den;
        }
    }
}

// ---------------- Kernel 2: routing ----------------
// One block per (b,o,h), 448 threads = (i,w). Reads the contiguous
// [i][w][d] ys slab (14336 B, L2/L3-resident), recomputes ns, then
// consensus / losses / kth-smallest (stable rank) / masked average.
__global__ __launch_bounds__(448) void k_route(const float* __restrict__ ys,
                                               float* __restrict__ out) {
    const int bid = blockIdx.x;  // (b*O + o)*H + h
    const int h = bid % H;
    const int o = (bid / H) % O;
    const int b = bid / (H * O);
    const int t = threadIdx.x;
    const int i = t / W, w = t - (t / W) * W;   // t == i*W + w

    __shared__ __align__(16) float ysl[YS_BLOCK];  // [i][w][d]
    __shared__ float ns_s[I * W];
    __shared__ float ls_s[I * W];
    __shared__ float vsh[D * W];
    __shared__ float thr_s[W];

    const f4* src = (const f4*)(ys + (size_t)bid * YS_BLOCK);
    f4* ysl4 = (f4*)ysl;
    ysl4[t] = src[t];
    ysl4[t + 448] = src[t + 448];
    __syncthreads();

    float y[D];
    float s2 = 0.f;
    #pragma unroll
    for (int d = 0; d < D; ++d) { y[d] = ysl[t * D + d]; s2 += y[d] * y[d]; }
    const float nsv = sqrtf(s2);
    ns_s[t] = nsv;
    __syncthreads();

    // consensus v[d][w] (112 threads)
    if (t < D * W) {
        const int d = t / W, w2 = t - (t / W) * W;
        float num = 0.f, dn = 0.f;
        #pragma unroll
        for (int j = 0; j < I; ++j) {
            float nv = ns_s[j * W + w2];
            num += nv * ysl[(j * W + w2) * D + d];
            dn += nv;
        }
        vsh[d * W + w2] = num / dn;
    }
    __syncthreads();

    // losses (all 448 threads; y in regs)
    float lv = 0.f;
    #pragma unroll
    for (int d = 0; d < D; ++d) lv += vsh[d * W + w] * y[d];
    lv = -lv;
    ls_s[t] = lv;
    __syncthreads();

    // kth smallest (k=SUBSET) via stable rank -> matches jnp.sort[...,25]
    int rank = 0;
    #pragma unroll
    for (int j = 0; j < I; ++j) {
        float lj = ls_s[j * W + w];
        rank += (lj < lv || (lj == lv && j < i)) ? 1 : 0;
    }
    if (rank == SUBSET - 1) thr_s[w] = lv;
    __syncthreads();

    // masked weighted average -> out[b][o][d][h][w] (112 threads)
    if (t < D * W) {
        const int d = t / W, w2 = t - (t / W) * W;
        const float tw = thr_s[w2];
        float num = 0.f, dn = 0.f;
        #pragma unroll
        for (int j = 0; j < I; ++j) {
            float ls = ls_s[j * W + w2];
            float m  = (ls <= tw) ? 1.f : 0.f;
            float nv = m * ns_s[j * W + w2];
            num += nv * ysl[(j * W + w2) * D + d];
            dn  += nv;
        }
        out[(((size_t)b * O + o) * D + d) * (H * W) + h * W + w2] = num / dn;
    }
}

extern "C" void kernel_launch(void* const* d_in, const int* in_sizes, int n_in,
                              void* d_out, int out_size, void* d_ws, size_t ws_size,
                              hipStream_t stream) {
    const float* x = (const float*)d_in[0];
    float* out = (float*)d_out;
    float* ys = (float*)d_ws;   // 12,845,056 floats = 51.4 MB < ws_size

    k_reduce<<<dim3(B * I * O), dim3(256), 0, stream>>>(x, ys);
    k_route<<<dim3(B * O * H), dim3(448), 0, stream>>>(ys, out);
}